// Round 6
// baseline (1519.070 us; speedup 1.0000x reference)
//
#include <hip/hip_runtime.h>

typedef unsigned short ushort_t;
typedef unsigned int uint_t;
typedef unsigned long long u64_t;
typedef unsigned short us8 __attribute__((ext_vector_type(8)));
typedef float f32x2 __attribute__((ext_vector_type(2)));

constexpr int B_ = 8, N_ = 8192, S_ = 1024, K_ = 32;
constexpr int M_ = B_ * S_ * K_;          // 262144
constexpr float R2_ = 0.04f;
constexpr float EPS_ = 1e-5f;

// ---------- helpers ----------
__device__ __forceinline__ float bf2f(ushort_t u) {
    union { uint_t i; float f; } v; v.i = ((uint_t)u) << 16; return v.f;
}
__device__ __forceinline__ ushort_t f2bf(float f) {
    union { float f; uint_t i; } v; v.f = f;
    uint_t i = v.i;
    uint_t r = (i + 0x7FFFu + ((i >> 16) & 1u)) >> 16;   // RNE
    return (ushort_t)r;
}

// Packed f32 math via VOP3P — per-component IEEE round-to-nearest, bitwise
// identical to the scalar ops (the backend won't form these on its own).
__device__ __forceinline__ f32x2 pk_sub(f32x2 a, f32x2 b) {
    f32x2 r;
    asm("v_pk_add_f32 %0, %1, %2 neg_lo:[0,1] neg_hi:[0,1]" : "=v"(r) : "v"(a), "v"(b));
    return r;
}
__device__ __forceinline__ f32x2 pk_mul(f32x2 a, f32x2 b) {
    f32x2 r; asm("v_pk_mul_f32 %0, %1, %2" : "=v"(r) : "v"(a), "v"(b)); return r;
}
__device__ __forceinline__ f32x2 pk_add(f32x2 a, f32x2 b) {
    f32x2 r; asm("v_pk_add_f32 %0, %1, %2" : "=v"(r) : "v"(a), "v"(b)); return r;
}

// DPP max-reduce of a packed u64 key (value_bits<<32 | complement_index).
// Requires value >= 0 so f32 bits are monotonic as unsigned.
template<int C> __device__ __forceinline__ u64_t dmaxk(u64_t k) {
    int lo = __builtin_amdgcn_mov_dpp((int)(uint_t)k, C, 0xf, 0xf, true);
    int hi = __builtin_amdgcn_mov_dpp((int)(uint_t)(k >> 32), C, 0xf, 0xf, true);
    u64_t o = ((u64_t)(uint_t)hi << 32) | (uint_t)lo;
    return o > k ? o : k;
}

// ---------- 1. FPS: pk-asm inner loop, DPP ror cross-wave reduce ----------
__global__ __launch_bounds__(512, 2)
void fps_kernel(const float* __restrict__ xyz, int* __restrict__ fps_idx) {
    constexpr int T = 512, PP = N_ / T / 2;    // 8 pairs = 16 points per thread
    const int b = blockIdx.x, t = threadIdx.x;
    const int lane = t & 63;
    const float* X = xyz + (size_t)b * 3 * N_;

    __shared__ float4 sxyz[N_];                // 128 KB
    __shared__ u64_t rk[2][8];

    f32x2 px[PP], py[PP], pz[PP];
    float dA[PP], dB[PP];                      // dist for pair components
#pragma unroll
    for (int i = 0; i < PP; ++i) {
        int n0 = t + (2 * i) * T, n1 = n0 + T;
        float x0 = X[n0], y0 = X[N_ + n0], z0 = X[2 * N_ + n0];
        float x1 = X[n1], y1 = X[N_ + n1], z1 = X[2 * N_ + n1];
        px[i] = f32x2{x0, x1}; py[i] = f32x2{y0, y1}; pz[i] = f32x2{z0, z1};
        sxyz[n0] = make_float4(x0, y0, z0, 0.0f);
        sxyz[n1] = make_float4(x1, y1, z1, 0.0f);
        dA[i] = 1e10f; dB[i] = 1e10f;
    }
    float cx = X[0], cy = X[N_], cz = X[2 * N_];
    int far = 0;
    __syncthreads();

    for (int s = 0; s < S_; ++s) {
        if (t == 0) fps_idx[b * S_ + s] = far;
        float bvx = -1.0f, bvy = -1.0f; int bix = 0, biy = 0;
        f32x2 c2x = f32x2{cx, cx}, c2y = f32x2{cy, cy}, c2z = f32x2{cz, cz};
#pragma unroll
        for (int i = 0; i < PP; ++i) {
            // exact reference order: ((dx*dx + dy*dy) + dz*dz), unfused, packed
            f32x2 dx = pk_sub(px[i], c2x);
            f32x2 dy = pk_sub(py[i], c2y);
            f32x2 dz = pk_sub(pz[i], c2z);
            f32x2 d = pk_add(pk_add(pk_mul(dx, dx), pk_mul(dy, dy)), pk_mul(dz, dz));
            float nd0 = fminf(dA[i], d.x);
            float nd1 = fminf(dB[i], d.y);
            dA[i] = nd0; dB[i] = nd1;
            if (nd0 > bvx) { bvx = nd0; bix = t + (2 * i) * T; }
            if (nd1 > bvy) { bvy = nd1; biy = t + (2 * i + 1) * T; }
        }
        // merge the two chains: max value, min index on tie
        float bv; int bi;
        if (bvy > bvx || (bvy == bvx && biy < bix)) { bv = bvy; bi = biy; }
        else { bv = bvx; bi = bix; }

        // wave reduce: packed key, result valid in lane 63
        u64_t key = ((u64_t)(uint_t)__float_as_int(bv) << 32) | (uint_t)(N_ - 1 - bi);
        key = dmaxk<0x111>(key);   // row_shr:1
        key = dmaxk<0x112>(key);   // row_shr:2
        key = dmaxk<0x114>(key);   // row_shr:4
        key = dmaxk<0x118>(key);   // row_shr:8
        key = dmaxk<0x142>(key);   // row_bcast:15
        key = dmaxk<0x143>(key);   // row_bcast:31

        int p = s & 1;
        if (lane == 63) rk[p][t >> 6] = key;
        __syncthreads();
        // cross-wave: broadcast read of key[lane&7], then 3 ror-max stages.
        // data has period 8 across each 16-lane row, so ror 1,2,4 (window 8)
        // gives every lane the max over all 8 wave keys.
        u64_t k = rk[p][lane & 7];
        k = dmaxk<0x121>(k);       // row_ror:1
        k = dmaxk<0x122>(k);       // row_ror:2
        k = dmaxk<0x124>(k);       // row_ror:4
        far = N_ - 1 - (int)(uint_t)k;
        float4 c = sxyz[far];      // single b128 LDS broadcast
        cx = c.x; cy = c.y; cz = c.z;
    }
}

// ---------- 2. gather new_xyz + write output 0 ----------
__global__ __launch_bounds__(256)
void gather_nxyz(const float* __restrict__ xyz, const int* __restrict__ fps_idx,
                 float* __restrict__ nxyz, float* __restrict__ out0) {
    int i = blockIdx.x * 256 + threadIdx.x;
    if (i >= B_ * S_) return;
    int b = i / S_, s = i % S_;
    int idx = fps_idx[i];
    const float* X = xyz + (size_t)b * 3 * N_;
    float x = X[idx], y = X[N_ + idx], z = X[2 * N_ + idx];
    nxyz[(size_t)i * 3 + 0] = x;
    nxyz[(size_t)i * 3 + 1] = y;
    nxyz[(size_t)i * 3 + 2] = z;
    out0[((size_t)b * 3 + 0) * S_ + s] = x;
    out0[((size_t)b * 3 + 1) * S_ + s] = y;
    out0[((size_t)b * 3 + 2) * S_ + s] = z;
}

// ---------- 3. ball query: one wave per query, ordered ballot compaction ----------
__global__ __launch_bounds__(256)
void ballq_kernel(const float* __restrict__ xyz, const float* __restrict__ nxyz,
                  int* __restrict__ gi) {
    int wid = (blockIdx.x * 256 + threadIdx.x) >> 6;
    int lane = threadIdx.x & 63;
    if (wid >= B_ * S_) return;
    int b = wid / S_;
    const float* X = xyz + (size_t)b * 3 * N_;
    float nx = nxyz[(size_t)wid * 3 + 0];
    float ny = nxyz[(size_t)wid * 3 + 1];
    float nz = nxyz[(size_t)wid * 3 + 2];
    float snew = __fadd_rn(__fadd_rn(__fmul_rn(nx, nx), __fmul_rn(ny, ny)), __fmul_rn(nz, nz));
    int cnt = 0; int firstn = 0;
    int* out = gi + (size_t)wid * K_;
    for (int c0 = 0; c0 < N_; c0 += 64) {
        int n = c0 + lane;
        float xx = X[n], xy = X[N_ + n], xz = X[2 * N_ + n];
        float sxn = __fadd_rn(__fadd_rn(__fmul_rn(xx, xx), __fmul_rn(xy, xy)), __fmul_rn(xz, xz));
        float dot = __fadd_rn(__fadd_rn(__fmul_rn(nx, xx), __fmul_rn(ny, xy)), __fmul_rn(nz, xz));
        float sq = __fsub_rn(__fadd_rn(snew, sxn), __fmul_rn(2.0f, dot));
        bool inr = !(sq > R2_);
        unsigned long long mask = __ballot(inr);
        if (cnt == 0 && mask) firstn = c0 + __builtin_ctzll(mask);
        int rank = __popcll(mask & ((1ull << lane) - 1ull));
        if (inr && cnt + rank < K_) out[cnt + rank] = n;
        cnt += (int)__popcll(mask);
        if (cnt >= K_) break;
    }
    if (cnt < K_ && lane >= cnt && lane < K_) out[lane] = firstn;
}

// ---------- 4. transpose points (B,64,N) f32 -> (B,N,64) bf16 ----------
__global__ __launch_bounds__(256)
void transpose_pts(const float* __restrict__ pts, ushort_t* __restrict__ ptT) {
    __shared__ ushort_t tile[64][66];
    int b = blockIdx.y; int n0 = blockIdx.x * 64;
    int tc = threadIdx.x & 63;
    int tr = threadIdx.x >> 6;
    const float* src = pts + (size_t)b * 64 * N_;
#pragma unroll
    for (int i = 0; i < 16; ++i) {
        int c = i * 4 + tr;
        tile[c][tc] = f2bf(src[(size_t)c * N_ + n0 + tc]);
    }
    __syncthreads();
#pragma unroll
    for (int i = 0; i < 16; ++i) {
        int nr = i * 4 + tr;
        ptT[((size_t)b * N_ + n0 + nr) * 64 + tc] = tile[tc][nr];
    }
}

// ---------- 5. transpose weights W[co][ci] -> WT[ci][co] ----------
__global__ void wt_kernel(const float* __restrict__ w0, const float* __restrict__ w1,
                          const float* __restrict__ w2, float* __restrict__ wt) {
    int l = blockIdx.x;
    const float* w = l == 0 ? w0 : (l == 1 ? w1 : w2);
    int CI = (l == 0) ? 67 : 64;
    int CO = (l == 2) ? 128 : 64;
    float* dst = wt + (l == 0 ? 0 : (l == 1 ? 67 * 64 : 67 * 64 + 64 * 64));
    for (int i = threadIdx.x; i < CI * CO; i += 256) {
        int c = i / CO, o = i % CO;
        dst[c * CO + o] = w[o * CI + c];
    }
}

// ---------- 6. layer: thread-per-point GEMM, scalar weight loads ----------
template<bool FUSED>
__global__ __launch_bounds__(256)
void layer_kernel(const ushort_t* __restrict__ xin,
                  const ushort_t* __restrict__ ptT,
                  const float* __restrict__ xyz,
                  const float* __restrict__ nxyz,
                  const int* __restrict__ gi,
                  const float* __restrict__ WT,     // [CI][COtot]
                  const float* __restrict__ bias,   // [COtot]
                  const float* __restrict__ abuf,   // a at [c], shift at [128+c]
                  ushort_t* __restrict__ y,         // [M][COtot]
                  int COtot) {
    int m = blockIdx.x * 256 + threadIdx.x;
    int os = blockIdx.y * 64;
    float acc[64];
#pragma unroll
    for (int o = 0; o < 64; ++o) acc[o] = bias[os + o];

    int idx = 0, b = 0;
    const ushort_t* row;
    if constexpr (FUSED) {
        idx = gi[m];
        b = m >> 15;                      // m / (S*K)
        row = ptT + ((size_t)b * N_ + idx) * 64;
    } else {
        row = xin + (size_t)m * 64;
    }
#pragma unroll
    for (int c8 = 0; c8 < 8; ++c8) {
        us8 v = *reinterpret_cast<const us8*>(row + c8 * 8);
#pragma unroll
        for (int j = 0; j < 8; ++j) {
            int c = c8 * 8 + j;
            float h = bf2f(v[j]);
            if constexpr (!FUSED) h = fmaxf(fmaf(abuf[c], h, abuf[128 + c]), 0.0f);
            const float* wr = WT + (size_t)c * COtot + os;
#pragma unroll
            for (int o = 0; o < 64; ++o) acc[o] = fmaf(h, wr[o], acc[o]);
        }
    }
    if constexpr (FUSED) {
        int s = (m >> 5) & (S_ - 1);
        const float* X = xyz + (size_t)b * 3 * N_;
        const float* nx = nxyz + ((size_t)(b * S_ + s)) * 3;
#pragma unroll
        for (int j = 0; j < 3; ++j) {
            float h = X[(size_t)j * N_ + idx] - nx[j];
            const float* wr = WT + (size_t)(64 + j) * COtot + os;
#pragma unroll
            for (int o = 0; o < 64; ++o) acc[o] = fmaf(h, wr[o], acc[o]);
        }
    }
    ushort_t* yr = y + (size_t)m * COtot + os;
#pragma unroll
    for (int v8 = 0; v8 < 8; ++v8) {
        us8 w;
#pragma unroll
        for (int j = 0; j < 8; ++j) w[j] = f2bf(acc[v8 * 8 + j]);
        *reinterpret_cast<us8*>(yr + v8 * 8) = w;
    }
}

// ---------- 7. per-channel sum / sumsq ----------
template<int CO>
__global__ __launch_bounds__(256)
void stats_kernel(const ushort_t* __restrict__ y, float* __restrict__ sums) {
    __shared__ float ls[256];
    int t = threadIdx.x;
    ls[t] = 0.0f;
    __syncthreads();
    int lane = t & 63;
    int wid = blockIdx.x * 4 + (t >> 6);
    int nw = gridDim.x * 4;
    if constexpr (CO == 64) {
        float s = 0, q = 0;
        for (int m = wid; m < M_; m += nw) {
            float v = bf2f(y[(size_t)m * 64 + lane]);
            s += v; q = fmaf(v, v, q);
        }
        atomicAdd(&ls[lane], s); atomicAdd(&ls[128 + lane], q);
    } else {
        float s0 = 0, q0 = 0, s1 = 0, q1 = 0;
        for (int m = wid; m < M_; m += nw) {
            uint_t v = *reinterpret_cast<const uint_t*>(y + (size_t)m * 128 + lane * 2);
            float a = bf2f((ushort_t)(v & 0xffff));
            float c = bf2f((ushort_t)(v >> 16));
            s0 += a; q0 = fmaf(a, a, q0);
            s1 += c; q1 = fmaf(c, c, q1);
        }
        int c0 = lane * 2;
        atomicAdd(&ls[c0], s0); atomicAdd(&ls[c0 + 1], s1);
        atomicAdd(&ls[128 + c0], q0); atomicAdd(&ls[128 + c0 + 1], q1);
    }
    __syncthreads();
    atomicAdd(&sums[t], ls[t]);
}

// ---------- 8. finalize BN affine: a = g/sqrt(v+eps), shift = be - mean*a ----------
__global__ void finalize_kernel(const float* __restrict__ sums, const float* __restrict__ g,
                                const float* __restrict__ be, float* __restrict__ ab, int CO) {
    int c = threadIdx.x;
    if (c < CO) {
        float mean = sums[c] * (1.0f / (float)M_);
        float var = sums[128 + c] * (1.0f / (float)M_) - mean * mean;
        float a = g[c] / sqrtf(var + EPS_);
        ab[c] = a;
        ab[128 + c] = be[c] - mean * a;
    }
}

// ---------- 9. final: BN + max over K + relu, write output 1 ----------
__global__ __launch_bounds__(256)
void final_max(const ushort_t* __restrict__ x3, const float* __restrict__ ab,
               float* __restrict__ out1) {
    int t = threadIdx.x;
    int gw = blockIdx.x * 4 + (t >> 6);
    if (gw >= B_ * S_) return;
    int lane = t & 63;
    int b = gw / S_, s = gw % S_;
    int c0 = lane * 2;
    float a0 = ab[c0], k0 = ab[128 + c0];
    float a1 = ab[c0 + 1], k1 = ab[128 + c0 + 1];
    const ushort_t* base = x3 + (size_t)gw * K_ * 128;
    float m0 = -1e30f, m1 = -1e30f;
#pragma unroll 8
    for (int k = 0; k < K_; ++k) {
        uint_t v = *reinterpret_cast<const uint_t*>(base + k * 128 + c0);
        float f0 = fmaf(bf2f((ushort_t)(v & 0xffff)), a0, k0);
        float f1 = fmaf(bf2f((ushort_t)(v >> 16)), a1, k1);
        m0 = fmaxf(m0, f0); m1 = fmaxf(m1, f1);
    }
    out1[((size_t)b * 128 + c0) * S_ + s] = fmaxf(m0, 0.0f);
    out1[((size_t)b * 128 + c0 + 1) * S_ + s] = fmaxf(m1, 0.0f);
}

// ---------- launch ----------
extern "C" void kernel_launch(void* const* d_in, const int* in_sizes, int n_in,
                              void* d_out, int out_size, void* d_ws, size_t ws_size,
                              hipStream_t stream) {
    const float* xyz = (const float*)d_in[0];
    const float* pts = (const float*)d_in[1];
    const float* w0 = (const float*)d_in[2];
    const float* b0 = (const float*)d_in[3];
    const float* g0 = (const float*)d_in[4];
    const float* be0 = (const float*)d_in[5];
    const float* w1 = (const float*)d_in[6];
    const float* b1 = (const float*)d_in[7];
    const float* g1 = (const float*)d_in[8];
    const float* be1 = (const float*)d_in[9];
    const float* w2 = (const float*)d_in[10];
    const float* b2 = (const float*)d_in[11];
    const float* g2 = (const float*)d_in[12];
    const float* be2 = (const float*)d_in[13];

    float* out0 = (float*)d_out;
    float* out1 = out0 + (size_t)B_ * 3 * S_;

    char* ws = (char*)d_ws;
    int*      fps   = (int*)(ws + 0);                 // 32 KB
    float*    nxyz  = (float*)(ws + 32768);           // 96 KB
    int*      gi    = (int*)(ws + 131072);            // 1 MB
    float*    stats = (float*)(ws + 1179648);         // 3 KB
    float*    ab    = (float*)(ws + 1182720);         // 3 KB
    float*    wt    = (float*)(ws + 1185792);         // 65 KB
    ushort_t* ptT   = (ushort_t*)(ws + 2097152);      // 8 MB
    ushort_t* xA    = (ushort_t*)(ws + 10485760);     // 67 MB (x1 stride 64, later x3 stride 128)
    ushort_t* xB    = (ushort_t*)(ws + 77594624);     // 33.5 MB (x2)

    hipMemsetAsync(stats, 0, 3 * 256 * sizeof(float), stream);
    wt_kernel<<<3, 256, 0, stream>>>(w0, w1, w2, wt);
    transpose_pts<<<dim3(N_ / 64, B_), 256, 0, stream>>>(pts, ptT);
    fps_kernel<<<B_, 512, 0, stream>>>(xyz, fps);
    gather_nxyz<<<(B_ * S_ + 255) / 256, 256, 0, stream>>>(xyz, fps, nxyz, out0);
    ballq_kernel<<<(B_ * S_) / 4, 256, 0, stream>>>(xyz, nxyz, gi);

    // layer 1 (fused gather) -> xA (stride 64)
    layer_kernel<true><<<dim3(M_ / 256, 1), 256, 0, stream>>>(
        xA, ptT, xyz, nxyz, gi, wt, b0, ab, xA, 64);
    stats_kernel<64><<<256, 256, 0, stream>>>(xA, stats + 0);
    finalize_kernel<<<1, 128, 0, stream>>>(stats + 0, g0, be0, ab + 0, 64);

    // layer 2 -> xB
    layer_kernel<false><<<dim3(M_ / 256, 1), 256, 0, stream>>>(
        xA, ptT, xyz, nxyz, gi, wt + 67 * 64, b1, ab + 0, xB, 64);
    stats_kernel<64><<<256, 256, 0, stream>>>(xB, stats + 256);
    finalize_kernel<<<1, 128, 0, stream>>>(stats + 256, g1, be1, ab + 256, 64);

    // layer 3 -> xA (stride 128)
    layer_kernel<false><<<dim3(M_ / 256, 2), 256, 0, stream>>>(
        xB, ptT, xyz, nxyz, gi, wt + 67 * 64 + 64 * 64, b2, ab + 256, xA, 128);
    stats_kernel<128><<<256, 256, 0, stream>>>(xA, stats + 512);
    finalize_kernel<<<1, 128, 0, stream>>>(stats + 512, g2, be2, ab + 512, 128);

    final_max<<<(B_ * S_) / 4, 256, 0, stream>>>(xA, ab + 512, out1);
}

// Round 7
// 1460.715 us; speedup vs baseline: 1.0399x; 1.0399x over previous
//
#include <hip/hip_runtime.h>

typedef unsigned short ushort_t;
typedef unsigned int uint_t;
typedef unsigned long long u64_t;
typedef unsigned short us8 __attribute__((ext_vector_type(8)));

constexpr int B_ = 8, N_ = 8192, S_ = 1024, K_ = 32;
constexpr int M_ = B_ * S_ * K_;          // 262144
constexpr float R2_ = 0.04f;
constexpr float EPS_ = 1e-5f;

// ---------- helpers ----------
__device__ __forceinline__ float bf2f(ushort_t u) {
    union { uint_t i; float f; } v; v.i = ((uint_t)u) << 16; return v.f;
}
__device__ __forceinline__ ushort_t f2bf(float f) {
    union { float f; uint_t i; } v; v.f = f;
    uint_t i = v.i;
    uint_t r = (i + 0x7FFFu + ((i >> 16) & 1u)) >> 16;   // RNE
    return (ushort_t)r;
}

// f32 DPP max helper (2 inst/stage). bound_ctrl=true -> OOB lanes read 0,
// safe because all reduced values are >= 0.
template<int C> __device__ __forceinline__ float dmaxf(float v) {
    int o = __builtin_amdgcn_mov_dpp(__float_as_int(v), C, 0xf, 0xf, true);
    return fmaxf(v, __int_as_float(o));
}

// ---------- 1. FPS: chunked ownership, value-only reduce, winner-only argmax ----------
// Thread t owns points [16t, 16t+16)  =>  lane order == index order, wave order
// == index order. Selection = max value, first occurrence => identical to
// jnp.argmax over distances computed in the reference association order.
__global__ __launch_bounds__(512, 2)
void fps_kernel(const float* __restrict__ xyz, int* __restrict__ fps_idx) {
    constexpr int T = 512, P = N_ / T;    // 16 points per thread
    const int b = blockIdx.x, t = threadIdx.x;
    const int lane = t & 63, w = t >> 6;
    const float* X = xyz + (size_t)b * 3 * N_;

    __shared__ float ssx[N_], ssy[N_], ssz[N_];   // identity layout, 96 KB
    __shared__ float rv[8];
    __shared__ int sfar;

    // coalesced global -> LDS
#pragma unroll
    for (int i = 0; i < P; ++i) {
        int n = t + i * T;
        ssx[n] = X[n]; ssy[n] = X[N_ + n]; ssz[n] = X[2 * N_ + n];
    }
    if (t == 0) fps_idx[b * S_] = 0;
    __syncthreads();

    // chunked re-read (one-time; bank conflicts acceptable)
    float px[P], py[P], pz[P], dist[P];
#pragma unroll
    for (int i = 0; i < P; ++i) {
        int n = t * P + i;
        px[i] = ssx[n]; py[i] = ssy[n]; pz[i] = ssz[n];
        dist[i] = 1e10f;
    }
    float cx = ssx[0], cy = ssy[0], cz = ssz[0];

    for (int s = 0; s < S_; ++s) {
        // exact reference order: ((dx*dx + dy*dy) + dz*dz), unfused
#pragma unroll
        for (int i = 0; i < P; ++i) {
            float dx = __fsub_rn(px[i], cx);
            float dy = __fsub_rn(py[i], cy);
            float dz = __fsub_rn(pz[i], cz);
            float d = __fadd_rn(__fadd_rn(__fmul_rn(dx, dx), __fmul_rn(dy, dy)), __fmul_rn(dz, dz));
            dist[i] = fminf(dist[i], d);
        }
        // in-thread tree max (value only)
        float a0 = fmaxf(dist[0], dist[8]);
        float a1 = fmaxf(dist[1], dist[9]);
        float a2 = fmaxf(dist[2], dist[10]);
        float a3 = fmaxf(dist[3], dist[11]);
        float a4 = fmaxf(dist[4], dist[12]);
        float a5 = fmaxf(dist[5], dist[13]);
        float a6 = fmaxf(dist[6], dist[14]);
        float a7 = fmaxf(dist[7], dist[15]);
        float b0 = fmaxf(fmaxf(a0, a4), fmaxf(a1, a5));
        float b1 = fmaxf(fmaxf(a2, a6), fmaxf(a3, a7));
        float lmax = fmaxf(b0, b1);
        // wave max via DPP, result in lane 63
        float m = lmax;
        m = dmaxf<0x111>(m);   // row_shr:1
        m = dmaxf<0x112>(m);   // row_shr:2
        m = dmaxf<0x114>(m);   // row_shr:4
        m = dmaxf<0x118>(m);   // row_shr:8
        m = dmaxf<0x142>(m);   // row_bcast:15
        m = dmaxf<0x143>(m);   // row_bcast:31
        if (lane == 63) rv[w] = m;
        __syncthreads();

        // cross-wave max: 8-periodic data, ror 1,2,4 covers all 8 values
        float kv0 = rv[lane & 7];
        float kv = kv0;
        kv = dmaxf<0x121>(kv);  // row_ror:1
        kv = dmaxf<0x122>(kv);  // row_ror:2
        kv = dmaxf<0x124>(kv);  // row_ror:4
        float gmax = kv;
        // first wave holding gmax (bit j of ballot == (rv[j&7]==gmax))
        u64_t wm = __ballot(kv0 == gmax);
        int first_w = __builtin_ctzll(wm);    // < 8

        if (w == first_w) {                   // wave-uniform branch
            u64_t lm = __ballot(lmax == gmax);
            int L = __builtin_ctzll(lm);      // lowest lane = lowest index
            if (lane == L) {
                int fi = 0;
#pragma unroll
                for (int i = P - 1; i >= 0; --i)
                    if (dist[i] == gmax) fi = i;   // lowest i wins
                int nf = t * P + fi;
                sfar = nf;
                if (s + 1 < S_) fps_idx[b * S_ + s + 1] = nf;
            }
        }
        __syncthreads();
        int nf = sfar;
        cx = ssx[nf]; cy = ssy[nf]; cz = ssz[nf];   // broadcast reads
    }
}

// ---------- 2. gather new_xyz + write output 0 ----------
__global__ __launch_bounds__(256)
void gather_nxyz(const float* __restrict__ xyz, const int* __restrict__ fps_idx,
                 float* __restrict__ nxyz, float* __restrict__ out0) {
    int i = blockIdx.x * 256 + threadIdx.x;
    if (i >= B_ * S_) return;
    int b = i / S_, s = i % S_;
    int idx = fps_idx[i];
    const float* X = xyz + (size_t)b * 3 * N_;
    float x = X[idx], y = X[N_ + idx], z = X[2 * N_ + idx];
    nxyz[(size_t)i * 3 + 0] = x;
    nxyz[(size_t)i * 3 + 1] = y;
    nxyz[(size_t)i * 3 + 2] = z;
    out0[((size_t)b * 3 + 0) * S_ + s] = x;
    out0[((size_t)b * 3 + 1) * S_ + s] = y;
    out0[((size_t)b * 3 + 2) * S_ + s] = z;
}

// ---------- 3. ball query: one wave per query, ordered ballot compaction ----------
__global__ __launch_bounds__(256)
void ballq_kernel(const float* __restrict__ xyz, const float* __restrict__ nxyz,
                  int* __restrict__ gi) {
    int wid = (blockIdx.x * 256 + threadIdx.x) >> 6;
    int lane = threadIdx.x & 63;
    if (wid >= B_ * S_) return;
    int b = wid / S_;
    const float* X = xyz + (size_t)b * 3 * N_;
    float nx = nxyz[(size_t)wid * 3 + 0];
    float ny = nxyz[(size_t)wid * 3 + 1];
    float nz = nxyz[(size_t)wid * 3 + 2];
    float snew = __fadd_rn(__fadd_rn(__fmul_rn(nx, nx), __fmul_rn(ny, ny)), __fmul_rn(nz, nz));
    int cnt = 0; int firstn = 0;
    int* out = gi + (size_t)wid * K_;
    for (int c0 = 0; c0 < N_; c0 += 64) {
        int n = c0 + lane;
        float xx = X[n], xy = X[N_ + n], xz = X[2 * N_ + n];
        float sxn = __fadd_rn(__fadd_rn(__fmul_rn(xx, xx), __fmul_rn(xy, xy)), __fmul_rn(xz, xz));
        float dot = __fadd_rn(__fadd_rn(__fmul_rn(nx, xx), __fmul_rn(ny, xy)), __fmul_rn(nz, xz));
        float sq = __fsub_rn(__fadd_rn(snew, sxn), __fmul_rn(2.0f, dot));
        bool inr = !(sq > R2_);
        unsigned long long mask = __ballot(inr);
        if (cnt == 0 && mask) firstn = c0 + __builtin_ctzll(mask);
        int rank = __popcll(mask & ((1ull << lane) - 1ull));
        if (inr && cnt + rank < K_) out[cnt + rank] = n;
        cnt += (int)__popcll(mask);
        if (cnt >= K_) break;
    }
    if (cnt < K_ && lane >= cnt && lane < K_) out[lane] = firstn;
}

// ---------- 4. transpose points (B,64,N) f32 -> (B,N,64) bf16 ----------
__global__ __launch_bounds__(256)
void transpose_pts(const float* __restrict__ pts, ushort_t* __restrict__ ptT) {
    __shared__ ushort_t tile[64][66];
    int b = blockIdx.y; int n0 = blockIdx.x * 64;
    int tc = threadIdx.x & 63;
    int tr = threadIdx.x >> 6;
    const float* src = pts + (size_t)b * 64 * N_;
#pragma unroll
    for (int i = 0; i < 16; ++i) {
        int c = i * 4 + tr;
        tile[c][tc] = f2bf(src[(size_t)c * N_ + n0 + tc]);
    }
    __syncthreads();
#pragma unroll
    for (int i = 0; i < 16; ++i) {
        int nr = i * 4 + tr;
        ptT[((size_t)b * N_ + n0 + nr) * 64 + tc] = tile[tc][nr];
    }
}

// ---------- 5. transpose weights W[co][ci] -> WT[ci][co] ----------
__global__ void wt_kernel(const float* __restrict__ w0, const float* __restrict__ w1,
                          const float* __restrict__ w2, float* __restrict__ wt) {
    int l = blockIdx.x;
    const float* w = l == 0 ? w0 : (l == 1 ? w1 : w2);
    int CI = (l == 0) ? 67 : 64;
    int CO = (l == 2) ? 128 : 64;
    float* dst = wt + (l == 0 ? 0 : (l == 1 ? 67 * 64 : 67 * 64 + 64 * 64));
    for (int i = threadIdx.x; i < CI * CO; i += 256) {
        int c = i / CO, o = i % CO;
        dst[c * CO + o] = w[o * CI + c];
    }
}

// ---------- 6. layer: thread-per-point GEMM, scalar weight loads ----------
template<bool FUSED>
__global__ __launch_bounds__(256)
void layer_kernel(const ushort_t* __restrict__ xin,
                  const ushort_t* __restrict__ ptT,
                  const float* __restrict__ xyz,
                  const float* __restrict__ nxyz,
                  const int* __restrict__ gi,
                  const float* __restrict__ WT,     // [CI][COtot]
                  const float* __restrict__ bias,   // [COtot]
                  const float* __restrict__ abuf,   // a at [c], shift at [128+c]
                  ushort_t* __restrict__ y,         // [M][COtot]
                  int COtot) {
    int m = blockIdx.x * 256 + threadIdx.x;
    int os = blockIdx.y * 64;
    float acc[64];
#pragma unroll
    for (int o = 0; o < 64; ++o) acc[o] = bias[os + o];

    int idx = 0, b = 0;
    const ushort_t* row;
    if constexpr (FUSED) {
        idx = gi[m];
        b = m >> 15;                      // m / (S*K)
        row = ptT + ((size_t)b * N_ + idx) * 64;
    } else {
        row = xin + (size_t)m * 64;
    }
#pragma unroll
    for (int c8 = 0; c8 < 8; ++c8) {
        us8 v = *reinterpret_cast<const us8*>(row + c8 * 8);
#pragma unroll
        for (int j = 0; j < 8; ++j) {
            int c = c8 * 8 + j;
            float h = bf2f(v[j]);
            if constexpr (!FUSED) h = fmaxf(fmaf(abuf[c], h, abuf[128 + c]), 0.0f);
            const float* wr = WT + (size_t)c * COtot + os;
#pragma unroll
            for (int o = 0; o < 64; ++o) acc[o] = fmaf(h, wr[o], acc[o]);
        }
    }
    if constexpr (FUSED) {
        int s = (m >> 5) & (S_ - 1);
        const float* X = xyz + (size_t)b * 3 * N_;
        const float* nx = nxyz + ((size_t)(b * S_ + s)) * 3;
#pragma unroll
        for (int j = 0; j < 3; ++j) {
            float h = X[(size_t)j * N_ + idx] - nx[j];
            const float* wr = WT + (size_t)(64 + j) * COtot + os;
#pragma unroll
            for (int o = 0; o < 64; ++o) acc[o] = fmaf(h, wr[o], acc[o]);
        }
    }
    ushort_t* yr = y + (size_t)m * COtot + os;
#pragma unroll
    for (int v8 = 0; v8 < 8; ++v8) {
        us8 w;
#pragma unroll
        for (int j = 0; j < 8; ++j) w[j] = f2bf(acc[v8 * 8 + j]);
        *reinterpret_cast<us8*>(yr + v8 * 8) = w;
    }
}

// ---------- 7. per-channel sum / sumsq ----------
template<int CO>
__global__ __launch_bounds__(256)
void stats_kernel(const ushort_t* __restrict__ y, float* __restrict__ sums) {
    __shared__ float ls[256];
    int t = threadIdx.x;
    ls[t] = 0.0f;
    __syncthreads();
    int lane = t & 63;
    int wid = blockIdx.x * 4 + (t >> 6);
    int nw = gridDim.x * 4;
    if constexpr (CO == 64) {
        float s = 0, q = 0;
        for (int m = wid; m < M_; m += nw) {
            float v = bf2f(y[(size_t)m * 64 + lane]);
            s += v; q = fmaf(v, v, q);
        }
        atomicAdd(&ls[lane], s); atomicAdd(&ls[128 + lane], q);
    } else {
        float s0 = 0, q0 = 0, s1 = 0, q1 = 0;
        for (int m = wid; m < M_; m += nw) {
            uint_t v = *reinterpret_cast<const uint_t*>(y + (size_t)m * 128 + lane * 2);
            float a = bf2f((ushort_t)(v & 0xffff));
            float c = bf2f((ushort_t)(v >> 16));
            s0 += a; q0 = fmaf(a, a, q0);
            s1 += c; q1 = fmaf(c, c, q1);
        }
        int c0 = lane * 2;
        atomicAdd(&ls[c0], s0); atomicAdd(&ls[c0 + 1], s1);
        atomicAdd(&ls[128 + c0], q0); atomicAdd(&ls[128 + c0 + 1], q1);
    }
    __syncthreads();
    atomicAdd(&sums[t], ls[t]);
}

// ---------- 8. finalize BN affine: a = g/sqrt(v+eps), shift = be - mean*a ----------
__global__ void finalize_kernel(const float* __restrict__ sums, const float* __restrict__ g,
                                const float* __restrict__ be, float* __restrict__ ab, int CO) {
    int c = threadIdx.x;
    if (c < CO) {
        float mean = sums[c] * (1.0f / (float)M_);
        float var = sums[128 + c] * (1.0f / (float)M_) - mean * mean;
        float a = g[c] / sqrtf(var + EPS_);
        ab[c] = a;
        ab[128 + c] = be[c] - mean * a;
    }
}

// ---------- 9. final: BN + max over K + relu, write output 1 ----------
__global__ __launch_bounds__(256)
void final_max(const ushort_t* __restrict__ x3, const float* __restrict__ ab,
               float* __restrict__ out1) {
    int t = threadIdx.x;
    int gw = blockIdx.x * 4 + (t >> 6);
    if (gw >= B_ * S_) return;
    int lane = t & 63;
    int b = gw / S_, s = gw % S_;
    int c0 = lane * 2;
    float a0 = ab[c0], k0 = ab[128 + c0];
    float a1 = ab[c0 + 1], k1 = ab[128 + c0 + 1];
    const ushort_t* base = x3 + (size_t)gw * K_ * 128;
    float m0 = -1e30f, m1 = -1e30f;
#pragma unroll 8
    for (int k = 0; k < K_; ++k) {
        uint_t v = *reinterpret_cast<const uint_t*>(base + k * 128 + c0);
        float f0 = fmaf(bf2f((ushort_t)(v & 0xffff)), a0, k0);
        float f1 = fmaf(bf2f((ushort_t)(v >> 16)), a1, k1);
        m0 = fmaxf(m0, f0); m1 = fmaxf(m1, f1);
    }
    out1[((size_t)b * 128 + c0) * S_ + s] = fmaxf(m0, 0.0f);
    out1[((size_t)b * 128 + c0 + 1) * S_ + s] = fmaxf(m1, 0.0f);
}

// ---------- launch ----------
extern "C" void kernel_launch(void* const* d_in, const int* in_sizes, int n_in,
                              void* d_out, int out_size, void* d_ws, size_t ws_size,
                              hipStream_t stream) {
    const float* xyz = (const float*)d_in[0];
    const float* pts = (const float*)d_in[1];
    const float* w0 = (const float*)d_in[2];
    const float* b0 = (const float*)d_in[3];
    const float* g0 = (const float*)d_in[4];
    const float* be0 = (const float*)d_in[5];
    const float* w1 = (const float*)d_in[6];
    const float* b1 = (const float*)d_in[7];
    const float* g1 = (const float*)d_in[8];
    const float* be1 = (const float*)d_in[9];
    const float* w2 = (const float*)d_in[10];
    const float* b2 = (const float*)d_in[11];
    const float* g2 = (const float*)d_in[12];
    const float* be2 = (const float*)d_in[13];

    float* out0 = (float*)d_out;
    float* out1 = out0 + (size_t)B_ * 3 * S_;

    char* ws = (char*)d_ws;
    int*      fps   = (int*)(ws + 0);                 // 32 KB
    float*    nxyz  = (float*)(ws + 32768);           // 96 KB
    int*      gi    = (int*)(ws + 131072);            // 1 MB
    float*    stats = (float*)(ws + 1179648);         // 3 KB
    float*    ab    = (float*)(ws + 1182720);         // 3 KB
    float*    wt    = (float*)(ws + 1185792);         // 65 KB
    ushort_t* ptT   = (ushort_t*)(ws + 2097152);      // 8 MB
    ushort_t* xA    = (ushort_t*)(ws + 10485760);     // 67 MB (x1 stride 64, later x3 stride 128)
    ushort_t* xB    = (ushort_t*)(ws + 77594624);     // 33.5 MB (x2)

    hipMemsetAsync(stats, 0, 3 * 256 * sizeof(float), stream);
    wt_kernel<<<3, 256, 0, stream>>>(w0, w1, w2, wt);
    transpose_pts<<<dim3(N_ / 64, B_), 256, 0, stream>>>(pts, ptT);
    fps_kernel<<<B_, 512, 0, stream>>>(xyz, fps);
    gather_nxyz<<<(B_ * S_ + 255) / 256, 256, 0, stream>>>(xyz, fps, nxyz, out0);
    ballq_kernel<<<(B_ * S_) / 4, 256, 0, stream>>>(xyz, nxyz, gi);

    // layer 1 (fused gather) -> xA (stride 64)
    layer_kernel<true><<<dim3(M_ / 256, 1), 256, 0, stream>>>(
        xA, ptT, xyz, nxyz, gi, wt, b0, ab, xA, 64);
    stats_kernel<64><<<256, 256, 0, stream>>>(xA, stats + 0);
    finalize_kernel<<<1, 128, 0, stream>>>(stats + 0, g0, be0, ab + 0, 64);

    // layer 2 -> xB
    layer_kernel<false><<<dim3(M_ / 256, 1), 256, 0, stream>>>(
        xA, ptT, xyz, nxyz, gi, wt + 67 * 64, b1, ab + 0, xB, 64);
    stats_kernel<64><<<256, 256, 0, stream>>>(xB, stats + 256);
    finalize_kernel<<<1, 128, 0, stream>>>(stats + 256, g1, be1, ab + 256, 64);

    // layer 3 -> xA (stride 128)
    layer_kernel<false><<<dim3(M_ / 256, 2), 256, 0, stream>>>(
        xB, ptT, xyz, nxyz, gi, wt + 67 * 64 + 64 * 64, b2, ab + 256, xA, 128);
    stats_kernel<128><<<256, 256, 0, stream>>>(xA, stats + 512);
    finalize_kernel<<<1, 128, 0, stream>>>(stats + 512, g2, be2, ab + 512, 128);

    final_max<<<(B_ * S_) / 4, 256, 0, stream>>>(xA, ab + 512, out1);
}

// Round 8
// 1401.906 us; speedup vs baseline: 1.0836x; 1.0419x over previous
//
#include <hip/hip_runtime.h>

typedef unsigned short ushort_t;
typedef unsigned int uint_t;
typedef unsigned long long u64_t;
typedef unsigned short us8 __attribute__((ext_vector_type(8)));

constexpr int B_ = 8, N_ = 8192, S_ = 1024, K_ = 32;
constexpr int M_ = B_ * S_ * K_;          // 262144
constexpr float R2_ = 0.04f;
constexpr float EPS_ = 1e-5f;

// ---------- helpers ----------
__device__ __forceinline__ float bf2f(ushort_t u) {
    union { uint_t i; float f; } v; v.i = ((uint_t)u) << 16; return v.f;
}
__device__ __forceinline__ ushort_t f2bf(float f) {
    union { float f; uint_t i; } v; v.f = f;
    uint_t i = v.i;
    uint_t r = (i + 0x7FFFu + ((i >> 16) & 1u)) >> 16;   // RNE
    return (ushort_t)r;
}

// f32 DPP max helper (2 inst/stage). bound_ctrl=true -> OOB lanes read 0,
// safe because all reduced values are >= 0.
template<int C> __device__ __forceinline__ float dmaxf(float v) {
    int o = __builtin_amdgcn_mov_dpp(__float_as_int(v), C, 0xf, 0xf, true);
    return fmaxf(v, __int_as_float(o));
}

// ---------- 1. FPS: 16 waves (4/SIMD) for latency hiding; chunked ownership ----------
// Thread t owns points [8t, 8t+8) => lane order == index order, wave order ==
// index order. Selection = max value, first occurrence => identical to
// jnp.argmax over distances computed in the reference association order.
__global__ __launch_bounds__(1024, 4)
void fps_kernel(const float* __restrict__ xyz, int* __restrict__ fps_idx) {
    constexpr int T = 1024, P = N_ / T;    // 8 points per thread
    const int b = blockIdx.x, t = threadIdx.x;
    const int lane = t & 63, w = t >> 6;   // 16 waves
    const float* X = xyz + (size_t)b * 3 * N_;

    __shared__ float4 sxyz[N_];            // 128 KB
    __shared__ float rv[16];
    __shared__ int sfar;

    // coalesced global -> LDS
#pragma unroll
    for (int i = 0; i < P; ++i) {
        int n = t + i * T;
        sxyz[n] = make_float4(X[n], X[N_ + n], X[2 * N_ + n], 0.0f);
    }
    if (t == 0) fps_idx[b * S_] = 0;
    __syncthreads();

    // chunked re-read (one-time; bank conflicts acceptable)
    float px[P], py[P], pz[P], dist[P];
#pragma unroll
    for (int i = 0; i < P; ++i) {
        float4 v = sxyz[t * P + i];
        px[i] = v.x; py[i] = v.y; pz[i] = v.z;
        dist[i] = 1e10f;
    }
    float4 cc = sxyz[0];
    float cx = cc.x, cy = cc.y, cz = cc.z;

    for (int s = 0; s < S_; ++s) {
        // exact reference order: ((dx*dx + dy*dy) + dz*dz), unfused
#pragma unroll
        for (int i = 0; i < P; ++i) {
            float dx = __fsub_rn(px[i], cx);
            float dy = __fsub_rn(py[i], cy);
            float dz = __fsub_rn(pz[i], cz);
            float d = __fadd_rn(__fadd_rn(__fmul_rn(dx, dx), __fmul_rn(dy, dy)), __fmul_rn(dz, dz));
            dist[i] = fminf(dist[i], d);
        }
        // in-thread tree max (value only)
        float a0 = fmaxf(dist[0], dist[4]);
        float a1 = fmaxf(dist[1], dist[5]);
        float a2 = fmaxf(dist[2], dist[6]);
        float a3 = fmaxf(dist[3], dist[7]);
        float lmax = fmaxf(fmaxf(a0, a1), fmaxf(a2, a3));
        // wave max via DPP, result in lane 63
        float m = lmax;
        m = dmaxf<0x111>(m);   // row_shr:1
        m = dmaxf<0x112>(m);   // row_shr:2
        m = dmaxf<0x114>(m);   // row_shr:4
        m = dmaxf<0x118>(m);   // row_shr:8
        m = dmaxf<0x142>(m);   // row_bcast:15
        m = dmaxf<0x143>(m);   // row_bcast:31
        if (lane == 63) rv[w] = m;
        __syncthreads();

        // cross-wave max: 16-periodic data, ror 1,2,4,8 covers the 16 values
        float kv0 = rv[lane & 15];
        float kv = kv0;
        kv = dmaxf<0x121>(kv);  // row_ror:1
        kv = dmaxf<0x122>(kv);  // row_ror:2
        kv = dmaxf<0x124>(kv);  // row_ror:4
        kv = dmaxf<0x128>(kv);  // row_ror:8
        float gmax = kv;
        // first wave holding gmax (bit j of ballot == (rv[j&15]==gmax), j<16)
        u64_t wm = __ballot(kv0 == gmax);
        int first_w = __builtin_ctzll(wm);    // < 16

        if (w == first_w) {                   // wave-uniform branch
            u64_t lm = __ballot(lmax == gmax);
            int L = __builtin_ctzll(lm);      // lowest lane = lowest index
            if (lane == L) {
                int fi = 0;
#pragma unroll
                for (int i = P - 1; i >= 0; --i)
                    if (dist[i] == gmax) fi = i;   // lowest i wins
                int nf = t * P + fi;
                sfar = nf;
                if (s + 1 < S_) fps_idx[b * S_ + s + 1] = nf;
            }
        }
        __syncthreads();
        int nf = sfar;
        float4 c = sxyz[nf];   // single b128 LDS broadcast
        cx = c.x; cy = c.y; cz = c.z;
    }
}

// ---------- 2. gather new_xyz + write output 0 ----------
__global__ __launch_bounds__(256)
void gather_nxyz(const float* __restrict__ xyz, const int* __restrict__ fps_idx,
                 float* __restrict__ nxyz, float* __restrict__ out0) {
    int i = blockIdx.x * 256 + threadIdx.x;
    if (i >= B_ * S_) return;
    int b = i / S_, s = i % S_;
    int idx = fps_idx[i];
    const float* X = xyz + (size_t)b * 3 * N_;
    float x = X[idx], y = X[N_ + idx], z = X[2 * N_ + idx];
    nxyz[(size_t)i * 3 + 0] = x;
    nxyz[(size_t)i * 3 + 1] = y;
    nxyz[(size_t)i * 3 + 2] = z;
    out0[((size_t)b * 3 + 0) * S_ + s] = x;
    out0[((size_t)b * 3 + 1) * S_ + s] = y;
    out0[((size_t)b * 3 + 2) * S_ + s] = z;
}

// ---------- 3. ball query: one wave per query, ordered ballot compaction ----------
__global__ __launch_bounds__(256)
void ballq_kernel(const float* __restrict__ xyz, const float* __restrict__ nxyz,
                  int* __restrict__ gi) {
    int wid = (blockIdx.x * 256 + threadIdx.x) >> 6;
    int lane = threadIdx.x & 63;
    if (wid >= B_ * S_) return;
    int b = wid / S_;
    const float* X = xyz + (size_t)b * 3 * N_;
    float nx = nxyz[(size_t)wid * 3 + 0];
    float ny = nxyz[(size_t)wid * 3 + 1];
    float nz = nxyz[(size_t)wid * 3 + 2];
    float snew = __fadd_rn(__fadd_rn(__fmul_rn(nx, nx), __fmul_rn(ny, ny)), __fmul_rn(nz, nz));
    int cnt = 0; int firstn = 0;
    int* out = gi + (size_t)wid * K_;
    for (int c0 = 0; c0 < N_; c0 += 64) {
        int n = c0 + lane;
        float xx = X[n], xy = X[N_ + n], xz = X[2 * N_ + n];
        float sxn = __fadd_rn(__fadd_rn(__fmul_rn(xx, xx), __fmul_rn(xy, xy)), __fmul_rn(xz, xz));
        float dot = __fadd_rn(__fadd_rn(__fmul_rn(nx, xx), __fmul_rn(ny, xy)), __fmul_rn(nz, xz));
        float sq = __fsub_rn(__fadd_rn(snew, sxn), __fmul_rn(2.0f, dot));
        bool inr = !(sq > R2_);
        unsigned long long mask = __ballot(inr);
        if (cnt == 0 && mask) firstn = c0 + __builtin_ctzll(mask);
        int rank = __popcll(mask & ((1ull << lane) - 1ull));
        if (inr && cnt + rank < K_) out[cnt + rank] = n;
        cnt += (int)__popcll(mask);
        if (cnt >= K_) break;
    }
    if (cnt < K_ && lane >= cnt && lane < K_) out[lane] = firstn;
}

// ---------- 4. transpose points (B,64,N) f32 -> (B,N,64) bf16 ----------
__global__ __launch_bounds__(256)
void transpose_pts(const float* __restrict__ pts, ushort_t* __restrict__ ptT) {
    __shared__ ushort_t tile[64][66];
    int b = blockIdx.y; int n0 = blockIdx.x * 64;
    int tc = threadIdx.x & 63;
    int tr = threadIdx.x >> 6;
    const float* src = pts + (size_t)b * 64 * N_;
#pragma unroll
    for (int i = 0; i < 16; ++i) {
        int c = i * 4 + tr;
        tile[c][tc] = f2bf(src[(size_t)c * N_ + n0 + tc]);
    }
    __syncthreads();
#pragma unroll
    for (int i = 0; i < 16; ++i) {
        int nr = i * 4 + tr;
        ptT[((size_t)b * N_ + n0 + nr) * 64 + tc] = tile[tc][nr];
    }
}

// ---------- 5. transpose weights W[co][ci] -> WT[ci][co] ----------
__global__ void wt_kernel(const float* __restrict__ w0, const float* __restrict__ w1,
                          const float* __restrict__ w2, float* __restrict__ wt) {
    int l = blockIdx.x;
    const float* w = l == 0 ? w0 : (l == 1 ? w1 : w2);
    int CI = (l == 0) ? 67 : 64;
    int CO = (l == 2) ? 128 : 64;
    float* dst = wt + (l == 0 ? 0 : (l == 1 ? 67 * 64 : 67 * 64 + 64 * 64));
    for (int i = threadIdx.x; i < CI * CO; i += 256) {
        int c = i / CO, o = i % CO;
        dst[c * CO + o] = w[o * CI + c];
    }
}

// ---------- 6. layer: thread-per-point GEMM, scalar weight loads ----------
template<bool FUSED>
__global__ __launch_bounds__(256)
void layer_kernel(const ushort_t* __restrict__ xin,
                  const ushort_t* __restrict__ ptT,
                  const float* __restrict__ xyz,
                  const float* __restrict__ nxyz,
                  const int* __restrict__ gi,
                  const float* __restrict__ WT,     // [CI][COtot]
                  const float* __restrict__ bias,   // [COtot]
                  const float* __restrict__ abuf,   // a at [c], shift at [128+c]
                  ushort_t* __restrict__ y,         // [M][COtot]
                  int COtot) {
    int m = blockIdx.x * 256 + threadIdx.x;
    int os = blockIdx.y * 64;
    float acc[64];
#pragma unroll
    for (int o = 0; o < 64; ++o) acc[o] = bias[os + o];

    int idx = 0, b = 0;
    const ushort_t* row;
    if constexpr (FUSED) {
        idx = gi[m];
        b = m >> 15;                      // m / (S*K)
        row = ptT + ((size_t)b * N_ + idx) * 64;
    } else {
        row = xin + (size_t)m * 64;
    }
#pragma unroll
    for (int c8 = 0; c8 < 8; ++c8) {
        us8 v = *reinterpret_cast<const us8*>(row + c8 * 8);
#pragma unroll
        for (int j = 0; j < 8; ++j) {
            int c = c8 * 8 + j;
            float h = bf2f(v[j]);
            if constexpr (!FUSED) h = fmaxf(fmaf(abuf[c], h, abuf[128 + c]), 0.0f);
            const float* wr = WT + (size_t)c * COtot + os;
#pragma unroll
            for (int o = 0; o < 64; ++o) acc[o] = fmaf(h, wr[o], acc[o]);
        }
    }
    if constexpr (FUSED) {
        int s = (m >> 5) & (S_ - 1);
        const float* X = xyz + (size_t)b * 3 * N_;
        const float* nx = nxyz + ((size_t)(b * S_ + s)) * 3;
#pragma unroll
        for (int j = 0; j < 3; ++j) {
            float h = X[(size_t)j * N_ + idx] - nx[j];
            const float* wr = WT + (size_t)(64 + j) * COtot + os;
#pragma unroll
            for (int o = 0; o < 64; ++o) acc[o] = fmaf(h, wr[o], acc[o]);
        }
    }
    ushort_t* yr = y + (size_t)m * COtot + os;
#pragma unroll
    for (int v8 = 0; v8 < 8; ++v8) {
        us8 w;
#pragma unroll
        for (int j = 0; j < 8; ++j) w[j] = f2bf(acc[v8 * 8 + j]);
        *reinterpret_cast<us8*>(yr + v8 * 8) = w;
    }
}

// ---------- 7. per-channel sum / sumsq ----------
template<int CO>
__global__ __launch_bounds__(256)
void stats_kernel(const ushort_t* __restrict__ y, float* __restrict__ sums) {
    __shared__ float ls[256];
    int t = threadIdx.x;
    ls[t] = 0.0f;
    __syncthreads();
    int lane = t & 63;
    int wid = blockIdx.x * 4 + (t >> 6);
    int nw = gridDim.x * 4;
    if constexpr (CO == 64) {
        float s = 0, q = 0;
        for (int m = wid; m < M_; m += nw) {
            float v = bf2f(y[(size_t)m * 64 + lane]);
            s += v; q = fmaf(v, v, q);
        }
        atomicAdd(&ls[lane], s); atomicAdd(&ls[128 + lane], q);
    } else {
        float s0 = 0, q0 = 0, s1 = 0, q1 = 0;
        for (int m = wid; m < M_; m += nw) {
            uint_t v = *reinterpret_cast<const uint_t*>(y + (size_t)m * 128 + lane * 2);
            float a = bf2f((ushort_t)(v & 0xffff));
            float c = bf2f((ushort_t)(v >> 16));
            s0 += a; q0 = fmaf(a, a, q0);
            s1 += c; q1 = fmaf(c, c, q1);
        }
        int c0 = lane * 2;
        atomicAdd(&ls[c0], s0); atomicAdd(&ls[c0 + 1], s1);
        atomicAdd(&ls[128 + c0], q0); atomicAdd(&ls[128 + c0 + 1], q1);
    }
    __syncthreads();
    atomicAdd(&sums[t], ls[t]);
}

// ---------- 8. finalize BN affine: a = g/sqrt(v+eps), shift = be - mean*a ----------
__global__ void finalize_kernel(const float* __restrict__ sums, const float* __restrict__ g,
                                const float* __restrict__ be, float* __restrict__ ab, int CO) {
    int c = threadIdx.x;
    if (c < CO) {
        float mean = sums[c] * (1.0f / (float)M_);
        float var = sums[128 + c] * (1.0f / (float)M_) - mean * mean;
        float a = g[c] / sqrtf(var + EPS_);
        ab[c] = a;
        ab[128 + c] = be[c] - mean * a;
    }
}

// ---------- 9. final: BN + max over K + relu, write output 1 ----------
__global__ __launch_bounds__(256)
void final_max(const ushort_t* __restrict__ x3, const float* __restrict__ ab,
               float* __restrict__ out1) {
    int t = threadIdx.x;
    int gw = blockIdx.x * 4 + (t >> 6);
    if (gw >= B_ * S_) return;
    int lane = t & 63;
    int b = gw / S_, s = gw % S_;
    int c0 = lane * 2;
    float a0 = ab[c0], k0 = ab[128 + c0];
    float a1 = ab[c0 + 1], k1 = ab[128 + c0 + 1];
    const ushort_t* base = x3 + (size_t)gw * K_ * 128;
    float m0 = -1e30f, m1 = -1e30f;
#pragma unroll 8
    for (int k = 0; k < K_; ++k) {
        uint_t v = *reinterpret_cast<const uint_t*>(base + k * 128 + c0);
        float f0 = fmaf(bf2f((ushort_t)(v & 0xffff)), a0, k0);
        float f1 = fmaf(bf2f((ushort_t)(v >> 16)), a1, k1);
        m0 = fmaxf(m0, f0); m1 = fmaxf(m1, f1);
    }
    out1[((size_t)b * 128 + c0) * S_ + s] = fmaxf(m0, 0.0f);
    out1[((size_t)b * 128 + c0 + 1) * S_ + s] = fmaxf(m1, 0.0f);
}

// ---------- launch ----------
extern "C" void kernel_launch(void* const* d_in, const int* in_sizes, int n_in,
                              void* d_out, int out_size, void* d_ws, size_t ws_size,
                              hipStream_t stream) {
    const float* xyz = (const float*)d_in[0];
    const float* pts = (const float*)d_in[1];
    const float* w0 = (const float*)d_in[2];
    const float* b0 = (const float*)d_in[3];
    const float* g0 = (const float*)d_in[4];
    const float* be0 = (const float*)d_in[5];
    const float* w1 = (const float*)d_in[6];
    const float* b1 = (const float*)d_in[7];
    const float* g1 = (const float*)d_in[8];
    const float* be1 = (const float*)d_in[9];
    const float* w2 = (const float*)d_in[10];
    const float* b2 = (const float*)d_in[11];
    const float* g2 = (const float*)d_in[12];
    const float* be2 = (const float*)d_in[13];

    float* out0 = (float*)d_out;
    float* out1 = out0 + (size_t)B_ * 3 * S_;

    char* ws = (char*)d_ws;
    int*      fps   = (int*)(ws + 0);                 // 32 KB
    float*    nxyz  = (float*)(ws + 32768);           // 96 KB
    int*      gi    = (int*)(ws + 131072);            // 1 MB
    float*    stats = (float*)(ws + 1179648);         // 3 KB
    float*    ab    = (float*)(ws + 1182720);         // 3 KB
    float*    wt    = (float*)(ws + 1185792);         // 65 KB
    ushort_t* ptT   = (ushort_t*)(ws + 2097152);      // 8 MB
    ushort_t* xA    = (ushort_t*)(ws + 10485760);     // 67 MB (x1 stride 64, later x3 stride 128)
    ushort_t* xB    = (ushort_t*)(ws + 77594624);     // 33.5 MB (x2)

    hipMemsetAsync(stats, 0, 3 * 256 * sizeof(float), stream);
    wt_kernel<<<3, 256, 0, stream>>>(w0, w1, w2, wt);
    transpose_pts<<<dim3(N_ / 64, B_), 256, 0, stream>>>(pts, ptT);
    fps_kernel<<<B_, 1024, 0, stream>>>(xyz, fps);
    gather_nxyz<<<(B_ * S_ + 255) / 256, 256, 0, stream>>>(xyz, fps, nxyz, out0);
    ballq_kernel<<<(B_ * S_) / 4, 256, 0, stream>>>(xyz, nxyz, gi);

    // layer 1 (fused gather) -> xA (stride 64)
    layer_kernel<true><<<dim3(M_ / 256, 1), 256, 0, stream>>>(
        xA, ptT, xyz, nxyz, gi, wt, b0, ab, xA, 64);
    stats_kernel<64><<<256, 256, 0, stream>>>(xA, stats + 0);
    finalize_kernel<<<1, 128, 0, stream>>>(stats + 0, g0, be0, ab + 0, 64);

    // layer 2 -> xB
    layer_kernel<false><<<dim3(M_ / 256, 1), 256, 0, stream>>>(
        xA, ptT, xyz, nxyz, gi, wt + 67 * 64, b1, ab + 0, xB, 64);
    stats_kernel<64><<<256, 256, 0, stream>>>(xB, stats + 256);
    finalize_kernel<<<1, 128, 0, stream>>>(stats + 256, g1, be1, ab + 256, 64);

    // layer 3 -> xA (stride 128)
    layer_kernel<false><<<dim3(M_ / 256, 2), 256, 0, stream>>>(
        xB, ptT, xyz, nxyz, gi, wt + 67 * 64 + 64 * 64, b2, ab + 256, xA, 128);
    stats_kernel<128><<<256, 256, 0, stream>>>(xA, stats + 512);
    finalize_kernel<<<1, 128, 0, stream>>>(stats + 512, g2, be2, ab + 512, 128);

    final_max<<<(B_ * S_) / 4, 256, 0, stream>>>(xA, ab + 512, out1);
}